// Round 11
// baseline (198.244 us; speedup 1.0000x reference)
//
#include <hip/hip_runtime.h>
#include <stdint.h>

// UnaryLinear (UnarySim stochastic linear), one clock, batch=1.
// out[o] = (acc[o] + sum_i f(i,o) + b_bit[o]) >= acc_bound
//   f = x[i] ? (w[o,i] >= brev8(rwi[o,i])) : !(w[o,i] >= brev8(rwii[o,i]))
// Sobol closed form rng[i] == bitreverse8(i): verified R4 (absmax = 0).
//
// R10: XCD-chunked slabs + nontemporal + x-hoist -> 70us to 42us (4.6 TB/s
// delivered reads). R11: same locality, deepen PER-WAVE issue: interleave
// BOTH rows' streams per chunk (6 independent nt loads/iter must be live
// simultaneously -> compiler can't shrink to VGPR=20 burst/drain).
// launch_bounds(256,6): VGPR cap ~85, 24 waves/CU, spill headroom (R7).

constexpr int IN_F  = 4096;
constexpr int OUT_F = 4096;
constexpr int NXCD  = 8;

typedef float v4f __attribute__((ext_vector_type(4)));
typedef int   v4i __attribute__((ext_vector_type(4)));

__device__ __forceinline__ float contrib(float w, int ii, int vi, float xf) {
    const float r  = (float)(__brev((unsigned)ii) >> 24);
    const float ri = (float)(__brev((unsigned)vi) >> 24);
    return (xf != 0.0f) ? ((w >= r) ? 1.0f : 0.0f)
                        : ((w >= ri) ? 0.0f : 1.0f);
}

__global__ __launch_bounds__(256, 6) void unary_linear_kernel(
    const float* __restrict__ x,            // [IN_F] in {0,1}
    const float* __restrict__ buf_wght,     // [OUT_F, IN_F]
    const float* __restrict__ buf_bias,     // [OUT_F]
    const float* __restrict__ acc,          // [OUT_F]
    const float* __restrict__ acc_bound,    // [1] = IN_F+1
    const int*   __restrict__ rng_wght_idx,     // [OUT_F, IN_F] in [0,256)
    const int*   __restrict__ rng_bias_idx,     // [OUT_F]
    const int*   __restrict__ rng_wght_idx_inv, // [OUT_F, IN_F]
    float*       __restrict__ out)          // [OUT_F]
{
    const int tid  = threadIdx.x;           // 0..255
    const int wave = tid >> 6;
    const int lane = tid & 63;

    // Bijective XCD-chunked mapping (grid=2048, 2048%8==0): xcd = blockIdx%8,
    // XCD k owns rows [k*512,(k+1)*512) -> contiguous 24MB slab per XCD-L2.
    const int xcd  = blockIdx.x & (NXCD - 1);
    const int slot = blockIdx.x >> 3;               // 0..255
    const int row0 = xcd * (OUT_F / NXCD) + slot * 2;
    const int row1 = row0 + 1;

    __shared__ float wsum[2][4];

    // Row-invariant x hoisted to registers (16 elems/thread, chip-wide reuse).
    v4f xv[4];
    #pragma unroll
    for (int i = 0; i < 4; ++i)
        xv[i] = *reinterpret_cast<const v4f*>(x + (i * 256 + tid) * 4);

    const float* __restrict__ w0p = buf_wght         + (size_t)row0 * IN_F;
    const int*   __restrict__ i0p = rng_wght_idx     + (size_t)row0 * IN_F;
    const int*   __restrict__ v0p = rng_wght_idx_inv + (size_t)row0 * IN_F;
    const float* __restrict__ w1p = buf_wght         + (size_t)row1 * IN_F;
    const int*   __restrict__ i1p = rng_wght_idx     + (size_t)row1 * IN_F;
    const int*   __restrict__ v1p = rng_wght_idx_inv + (size_t)row1 * IN_F;

    float sum0 = 0.0f, sum1 = 0.0f;

    // 6 independent nt streams per iteration: all 6 results must be live
    // before consumption -> forces real issue depth per wave.
    #pragma unroll
    for (int i = 0; i < 4; ++i) {
        const int base = (i * 256 + tid) * 4;   // coalesced 16B/lane
        const v4f w0 = __builtin_nontemporal_load(reinterpret_cast<const v4f*>(w0p + base));
        const v4i i0 = __builtin_nontemporal_load(reinterpret_cast<const v4i*>(i0p + base));
        const v4i v0 = __builtin_nontemporal_load(reinterpret_cast<const v4i*>(v0p + base));
        const v4f w1 = __builtin_nontemporal_load(reinterpret_cast<const v4f*>(w1p + base));
        const v4i i1 = __builtin_nontemporal_load(reinterpret_cast<const v4i*>(i1p + base));
        const v4i v1 = __builtin_nontemporal_load(reinterpret_cast<const v4i*>(v1p + base));

        sum0 += contrib(w0.x, i0.x, v0.x, xv[i].x)
              + contrib(w0.y, i0.y, v0.y, xv[i].y)
              + contrib(w0.z, i0.z, v0.z, xv[i].z)
              + contrib(w0.w, i0.w, v0.w, xv[i].w);
        sum1 += contrib(w1.x, i1.x, v1.x, xv[i].x)
              + contrib(w1.y, i1.y, v1.y, xv[i].y)
              + contrib(w1.z, i1.z, v1.z, xv[i].z)
              + contrib(w1.w, i1.w, v1.w, xv[i].w);
    }

    // wave butterfly reduce (64 lanes), both rows
    #pragma unroll
    for (int off = 32; off > 0; off >>= 1) {
        sum0 += __shfl_down(sum0, off);
        sum1 += __shfl_down(sum1, off);
    }

    if (lane == 0) { wsum[0][wave] = sum0; wsum[1][wave] = sum1; }
    __syncthreads();

    if (tid < 2) {
        const int row = (tid == 0) ? row0 : row1;
        const float rb = (float)(__brev((unsigned)rng_bias_idx[row]) >> 24);
        const float b_bit = (buf_bias[row] >= rb) ? 1.0f : 0.0f;
        const float total = acc[row] + wsum[tid][0] + wsum[tid][1]
                          + wsum[tid][2] + wsum[tid][3] + b_bit;
        out[row] = (total >= acc_bound[0]) ? 1.0f : 0.0f;
    }
}

extern "C" void kernel_launch(void* const* d_in, const int* in_sizes, int n_in,
                              void* d_out, int out_size, void* d_ws, size_t ws_size,
                              hipStream_t stream)
{
    // setup_inputs() order:
    // 0:x 1:buf_wght 2:buf_bias 3:rng 4:acc 5:acc_bound
    // 6:rng_wght_idx 7:rng_bias_idx 8:rng_wght_idx_inv
    const float* x         = (const float*)d_in[0];
    const float* buf_wght  = (const float*)d_in[1];
    const float* buf_bias  = (const float*)d_in[2];
    // d_in[3] = rng table — unused (closed form: rng[i] == bitreverse8(i))
    const float* acc       = (const float*)d_in[4];
    const float* acc_bound = (const float*)d_in[5];
    const int*   rwi       = (const int*)d_in[6];
    const int*   rbi       = (const int*)d_in[7];
    const int*   rwii      = (const int*)d_in[8];
    float* out = (float*)d_out;

    dim3 grid(2048);        // 2 rows/block; 2048%8==0 -> bijective XCD chunks
    dim3 block(256);
    hipLaunchKernelGGL(unary_linear_kernel, grid, block, 0, stream,
                       x, buf_wght, buf_bias, acc, acc_bound,
                       rwi, rbi, rwii, out);
}